// Round 2
// baseline (203.386 us; speedup 1.0000x reference)
//
#include <hip/hip_runtime.h>
#include <math.h>

#define S_LEN 2048
#define NH    16
#define DD    128
#define SROW  (NH*DD)      // 2048 elems between consecutive s
#define WIN2  512          // merged window (two streams union)
#define BQ    128          // queries per workgroup (8 waves x 16 q)
#define BK    64           // keys per chunk
#define RSQ   136          // LDS stride for d-major rows (128 elems + 8 pad)
#define RS    72           // LDS stride for key-major rows (64 elems + 8 pad)

typedef __bf16 bf16x8 __attribute__((ext_vector_type(8)));
typedef __bf16 bf16x4 __attribute__((ext_vector_type(4)));
typedef float  f32x4  __attribute__((ext_vector_type(4)));

__device__ __forceinline__ f32x4 mfma16(bf16x8 a, bf16x8 b, f32x4 c) {
    return __builtin_amdgcn_mfma_f32_16x16x32_bf16(a, b, c, 0, 0, 0);
}

__device__ __forceinline__ unsigned int pack_bf16(float lo, float hi) {
    return (unsigned int)__builtin_bit_cast(unsigned short, (__bf16)lo)
         | ((unsigned int)__builtin_bit_cast(unsigned short, (__bf16)hi) << 16);
}

// Shared layout (bf16 elems):
//   [0,      8704) : sK   64 rows x RSQ  ([key][d])
//   [8704,  17920) : sVt 128 rows x RS   ([d][key], column-swizzled)
//   [17920, 27136) : sP   8 waves x 16 x RS ([q][key])
// Q staging transiently overlays [0, 17408) (128 rows x RSQ) pre-loop.
#define OFF_VT 8704
#define OFF_P  17920
#define SMEM_ELEMS 27136

// ---- T14 staging helpers as macros over NAMED float4 registers ----
// (No arrays, no lambda: taking the address of the prefetch values forces
//  them to scratch — that was round-1's +17 MB WRITE_SIZE regression.)
#define CVT_K(v, it) do {                                                     \
    bf16x4 o4_ = { (__bf16)(v).x, (__bf16)(v).y, (__bf16)(v).z, (__bf16)(v).w }; \
    *(bf16x4*)&smem[(kRow + (it)*16) * RSQ + kCol] = o4_; } while (0)

// V chunk transposed+swizzled: V^T[d][key ^ ((d>>2)&7)<<3]
// Wave handles 8 keys (pair per iter); pair-exchange via shfl_xor(32);
// gv=0 writes d-rows 4rv,4rv+1; gv=1 writes 4rv+2,4rv+3 (2-key b32 each).
#define CVT_V(v4, it) do {                                                    \
    const int k0l_ = w*8 + (it)*2;                                            \
    float ox_ = __shfl_xor((v4).x, 32);                                       \
    float oy_ = __shfl_xor((v4).y, 32);                                       \
    float oz_ = __shfl_xor((v4).z, 32);                                       \
    float ow_ = __shfl_xor((v4).w, 32);                                       \
    float lo0_, hi0_, lo1_, hi1_; int d0_;                                    \
    if (gv == 0) { lo0_ = (v4).x; hi0_ = ox_;    lo1_ = (v4).y; hi1_ = oy_;    d0_ = 4*rv; } \
    else         { lo0_ = oz_;    hi0_ = (v4).z; lo1_ = ow_;    hi1_ = (v4).w; d0_ = 4*rv + 2; } \
    int col_ = k0l_ ^ ((rv & 7) << 3);   /* (d0>>2)&7 == rv for both rows */  \
    *(unsigned int*)&smem[OFF_VT + (d0_    ) * RS + col_] = pack_bf16(lo0_, hi0_); \
    *(unsigned int*)&smem[OFF_VT + (d0_ + 1) * RS + col_] = pack_bf16(lo1_, hi1_); } while (0)

#define STAGE_WRITE() do {                                                    \
    CVT_K(kv0, 0); CVT_K(kv1, 1); CVT_K(kv2, 2); CVT_K(kv3, 3);               \
    CVT_V(vv0, 0); CVT_V(vv1, 1); CVT_V(vv2, 2); CVT_V(vv3, 3); } while (0)

#define LOAD_CHUNK(c) do {                                                    \
    kv0 = *(const float4*)(Kp + (size_t)((c) + kRow +  0) * SROW);            \
    kv1 = *(const float4*)(Kp + (size_t)((c) + kRow + 16) * SROW);            \
    kv2 = *(const float4*)(Kp + (size_t)((c) + kRow + 32) * SROW);            \
    kv3 = *(const float4*)(Kp + (size_t)((c) + kRow + 48) * SROW);            \
    vv0 = *(const float4*)(Vp + (size_t)((c) + 0) * SROW);                    \
    vv1 = *(const float4*)(Vp + (size_t)((c) + 2) * SROW);                    \
    vv2 = *(const float4*)(Vp + (size_t)((c) + 4) * SROW);                    \
    vv3 = *(const float4*)(Vp + (size_t)((c) + 6) * SROW); } while (0)

__global__ __launch_bounds__(512, 4)
void swattn_kernel(const float* __restrict__ Qg, const float* __restrict__ Kg,
                   const float* __restrict__ Vg, float* __restrict__ Og) {
    __shared__ __align__(16) __bf16 smem[SMEM_ELEMS];

    const int t   = threadIdx.x;
    const int w   = t >> 6;        // wave 0..7
    const int l   = t & 63;        // lane
    const int r16 = l & 15;
    const int g4  = l >> 4;        // quarter-wave 0..3
    const int Qlo = blockIdx.x * BQ;
    const int h   = blockIdx.y;
    const int b   = blockIdx.z;

    const size_t bh = ((size_t)b * S_LEN) * SROW + (size_t)h * DD;
    const float C1 = 0.08838834764831845f * 1.44269504088896340f;  // scale * log2(e)

    // ---------- stage Q tile -> LDS bf16, C1 pre-folded ----------
    for (int it = 0; it < 8; ++it) {
        int f   = it * 512 + t;
        int q_l = f >> 5;          // 0..127
        int dq  = (f & 31) * 4;
        const float4 v = *(const float4*)&Qg[bh + (size_t)(Qlo + q_l) * SROW + dq];
        bf16x4 o4 = { (__bf16)(v.x * C1), (__bf16)(v.y * C1),
                      (__bf16)(v.z * C1), (__bf16)(v.w * C1) };
        *(bf16x4*)&smem[q_l * RSQ + dq] = o4;
    }
    __syncthreads();

    bf16x8 qf[4];   // B-operand frags, n=q=lane&15, k=d (wave owns 16 q)
#pragma unroll
    for (int sl = 0; sl < 4; ++sl)
        qf[sl] = *(const bf16x8*)&smem[(w*16 + r16) * RSQ + sl*32 + g4*8];
    __syncthreads();

    const f32x4 zero4 = {0.f, 0.f, 0.f, 0.f};
    f32x4 oacc[8];   // O^T frags: lane holds d=dg*16+4*g4+reg, q=r16
#pragma unroll
    for (int dg = 0; dg < 8; ++dg) oacc[dg] = zero4;
    float m_run = -1e4f;   // finite init: masked exp2 underflows to exact 0, no guard needed
    float l_run = 0.f;

    const int q_w = Qlo + w * 16;   // wave's first query
    const int gv = l >> 5;          // V-staging: which key of the pair
    const int rv = l & 31;          // V-staging: d-quad index

    // staging geometry (hoisted; f = it*512+t -> row = it*16 + (t>>5), col = (t&31)*4)
    const int kRow = t >> 5;          // 0..15
    const int kCol = (t & 31) * 4;    // 0..124
    const float* Kp = Kg + bh + kCol;
    const float* Vp = Vg + bh + (size_t)(w*8 + gv) * SROW + 4*rv;

    int cb = Qlo - (WIN2 - 1);
    if (cb < 0) cb = 0;
    cb &= ~(BK - 1);
    const int Qhi = Qlo + BQ - 1;

    // Prefetch registers (T14 issue-early / write-late). 8 named float4 =
    // 32 VGPRs, live across compute; no address ever taken -> stays in regs.
    float4 kv0, kv1, kv2, kv3, vv0, vv1, vv2, vv3;

    // ---------- prologue: load + stage first chunk ----------
    LOAD_CHUNK(cb);
    STAGE_WRITE();
    __syncthreads();

    for (int c0 = cb; c0 <= Qhi; c0 += BK) {
        const int cn  = c0 + BK;
        const bool pfn = (cn <= Qhi);          // block-uniform
        // ---- issue next chunk's loads NOW; latency hides under compute ----
        if (pfn) LOAD_CHUNK(cn);

        const bool act = (q_w + 15 >= c0) && (q_w <= c0 + (BK - 1) + (WIN2 - 1));
        if (act) {
            // ---- S^T = K · Q^T : C-layout lane: key=kg*16+4*g4+reg, q=r16 ----
            f32x4 st[4] = { zero4, zero4, zero4, zero4 };
            __builtin_amdgcn_s_setprio(1);
#pragma unroll
            for (int sl = 0; sl < 4; ++sl)
#pragma unroll
                for (int kg = 0; kg < 4; ++kg) {
                    bf16x8 kf = *(const bf16x8*)&smem[(kg*16 + r16) * RSQ + sl*32 + g4*8];
                    st[kg] = mfma16(kf, qf[sl], st[kg]);
                }
            __builtin_amdgcn_s_setprio(0);

            // ---- mask (C1 already folded into Q) ----
            const bool fv = (q_w >= c0 + (BK - 1)) && (q_w + 15 <= c0 + (WIN2 - 1));
            if (!fv) {
                int iq = q_w + r16;
#pragma unroll
                for (int kg = 0; kg < 4; ++kg) {
                    int relb = iq - (c0 + kg*16 + 4*g4);
#pragma unroll
                    for (int rg = 0; rg < 4; ++rg) {
                        bool ok = ((unsigned)(relb - rg)) < (unsigned)WIN2;
                        st[kg][rg] = ok ? st[kg][rg] : -1e30f;
                    }
                }
            }

            // ---- online softmax (in-lane over 16 keys; 2 shfls per stat) ----
            float mc = -1e30f;
#pragma unroll
            for (int kg = 0; kg < 4; ++kg)
#pragma unroll
                for (int rg = 0; rg < 4; ++rg) mc = fmaxf(mc, st[kg][rg]);
            mc = fmaxf(mc, __shfl_xor(mc, 16));
            mc = fmaxf(mc, __shfl_xor(mc, 32));
            float mn = fmaxf(m_run, mc);
            float alpha = exp2f(m_run - mn);
            m_run = mn;
            float sum = 0.f;
#pragma unroll
            for (int kg = 0; kg < 4; ++kg)
#pragma unroll
                for (int rg = 0; rg < 4; ++rg) {
                    float p = exp2f(st[kg][rg] - mn);   // masked -> exact 0 (mn >= -1e4)
                    st[kg][rg] = p;
                    sum += p;
                }
            sum += __shfl_xor(sum, 16);
            sum += __shfl_xor(sum, 32);
            l_run = l_run * alpha + sum;

            // ---- P -> sP [q][key] bf16 (lane's 4 regs = 4 consecutive keys) ----
#pragma unroll
            for (int kg = 0; kg < 4; ++kg) {
                f32x4 pv = st[kg];
                bf16x4 p4 = { (__bf16)pv[0], (__bf16)pv[1], (__bf16)pv[2], (__bf16)pv[3] };
                *(bf16x4*)&smem[OFF_P + (w*16 + r16) * RS + kg*16 + 4*g4] = p4;
            }

            // ---- rescale O ----
#pragma unroll
            for (int dg = 0; dg < 8; ++dg)
#pragma unroll
                for (int rg = 0; rg < 4; ++rg) oacc[dg][rg] *= alpha;

            // ---- O^T += V^T · P^T : A=V^T frag (m=d), B=P frag (n=q) ----
            __builtin_amdgcn_s_setprio(1);
#pragma unroll
            for (int ks = 0; ks < 2; ++ks) {
                bf16x8 pf = *(const bf16x8*)&smem[OFF_P + (w*16 + r16) * RS + ks*32 + g4*8];
#pragma unroll
                for (int dg = 0; dg < 8; ++dg) {
                    // un-swizzle: ((dg*16+r16)>>2)&7 == 4*(dg&1) + (r16>>2)
                    int col = (ks*32 + g4*8) ^ (32*(dg&1) + 8*(r16>>2));
                    bf16x8 vf = *(const bf16x8*)&smem[OFF_VT + (dg*16 + r16) * RS + col];
                    oacc[dg] = mfma16(vf, pf, oacc[dg]);
                }
            }
            __builtin_amdgcn_s_setprio(0);
        }
        __syncthreads();           // all waves done reading this chunk's K/V
        if (pfn) STAGE_WRITE();    // vmcnt-wait + cvt + ds_write (write-late)
        __syncthreads();           // next chunk's LDS ready
    }

    // ---------- epilogue: normalize and store (float4 along d) ----------
    float inv = 1.f / l_run;
    int q = q_w + r16;
    size_t base = bh + (size_t)q * SROW;
#pragma unroll
    for (int dg = 0; dg < 8; ++dg) {
        f32x4 o = oacc[dg];
        float4 res = { o[0]*inv, o[1]*inv, o[2]*inv, o[3]*inv };
        *(float4*)&Og[base + dg*16 + 4*g4] = res;
    }
}

extern "C" void kernel_launch(void* const* d_in, const int* in_sizes, int n_in,
                              void* d_out, int out_size, void* d_ws, size_t ws_size,
                              hipStream_t stream) {
    const float* q = (const float*)d_in[0];
    const float* k = (const float*)d_in[1];
    const float* v = (const float*)d_in[2];
    float* o = (float*)d_out;
    int B = in_sizes[0] / (S_LEN * NH * DD);
    dim3 grid(S_LEN / BQ, NH, B);
    swattn_kernel<<<grid, 512, 0, stream>>>(q, k, v, o);
}

// Round 3
// 168.471 us; speedup vs baseline: 1.2073x; 1.2073x over previous
//
#include <hip/hip_runtime.h>
#include <math.h>

#define S_LEN 2048
#define NH    16
#define DD    128
#define SROW  (NH*DD)      // 2048 elems between consecutive s
#define WIN2  512          // merged window (two streams union)
#define BQ    128          // queries per workgroup (8 waves x 16 q)
#define BK    32           // keys per chunk (halved: enables dbuf + 16-reg prefetch)
#define RSQ   136          // LDS stride for K rows: 128 d + 8 pad
#define RSV   56           // LDS stride for V^T rows: 32 keys + 24 pad (bank spread)
#define RSP   40           // LDS stride for sP rows: 32 keys + 8 pad

typedef __bf16 bf16x8 __attribute__((ext_vector_type(8)));
typedef __bf16 bf16x4 __attribute__((ext_vector_type(4)));
typedef float  f32x4  __attribute__((ext_vector_type(4)));

__device__ __forceinline__ f32x4 mfma16(bf16x8 a, bf16x8 b, f32x4 c) {
    return __builtin_amdgcn_mfma_f32_16x16x32_bf16(a, b, c, 0, 0, 0);
}

__device__ __forceinline__ unsigned int pack_bf16(float lo, float hi) {
    return (unsigned int)__builtin_bit_cast(unsigned short, (__bf16)lo)
         | ((unsigned int)__builtin_bit_cast(unsigned short, (__bf16)hi) << 16);
}

// Shared layout (bf16 elems), double-buffered K/V + single per-wave-private sP:
//   buf0: K [0, 4352)        V^T [4352, 11520)
//   buf1: K [11520, 15872)   V^T [15872, 23040)
//   sP  : [23040, 28160)   (8 waves x 16 q x RSP — wave-private, no dbuf needed)
// Q staging transiently overlays [0, 17408) pre-loop.
#define OFF_V0 4352
#define OFF_K1 11520
#define OFF_V1 15872
#define OFF_P  23040
#define SMEM_ELEMS 28160   // 56320 B -> 2 blocks/CU fit easily

// ---- staging over NAMED float4 regs (addresses never taken -> no scratch) ----
#define LOAD_CHUNK(c) do {                                                    \
    kv0 = *(const float4*)(Kp + (size_t)((c) + kRow     ) * SROW);            \
    kv1 = *(const float4*)(Kp + (size_t)((c) + kRow + 16) * SROW);            \
    vv0 = *(const float4*)(Vp + (size_t)((c) + 0) * SROW);                    \
    vv1 = *(const float4*)(Vp + (size_t)((c) + 2) * SROW); } while (0)

#define CVT_K(v, it, bK) do {                                                 \
    bf16x4 o4_ = { (__bf16)(v).x, (__bf16)(v).y, (__bf16)(v).z, (__bf16)(v).w }; \
    *(bf16x4*)&smem[(bK) + (kRow + (it)*16) * RSQ + kCol] = o4_; } while (0)

// V chunk transposed+swizzled: 16B-granule XOR within 32-key rows:
//   pcol = k0l ^ ((rv&3)<<3)  (granule bits 3..4 of elem index)
// Wave handles 4 keys (pair per iter); pair-exchange via shfl_xor(32);
// gv=0 writes d-rows 4rv,4rv+1; gv=1 writes 4rv+2,4rv+3 (2-key b32 each).
#define CVT_V(v4, it, bV) do {                                                \
    const int k0l_ = w*4 + (it)*2;                                            \
    float ox_ = __shfl_xor((v4).x, 32);                                       \
    float oy_ = __shfl_xor((v4).y, 32);                                       \
    float oz_ = __shfl_xor((v4).z, 32);                                       \
    float ow_ = __shfl_xor((v4).w, 32);                                       \
    float lo0_, hi0_, lo1_, hi1_; int d0_;                                    \
    if (gv == 0) { lo0_ = (v4).x; hi0_ = ox_;    lo1_ = (v4).y; hi1_ = oy_;    d0_ = 4*rv; } \
    else         { lo0_ = oz_;    hi0_ = (v4).z; lo1_ = ow_;    hi1_ = (v4).w; d0_ = 4*rv + 2; } \
    int col_ = k0l_ ^ ((rv & 3) << 3);                                        \
    *(unsigned int*)&smem[(bV) + (d0_    ) * RSV + col_] = pack_bf16(lo0_, hi0_); \
    *(unsigned int*)&smem[(bV) + (d0_ + 1) * RSV + col_] = pack_bf16(lo1_, hi1_); } while (0)

#define STAGE_WRITE(bK, bV) do {                                              \
    CVT_K(kv0, 0, bK); CVT_K(kv1, 1, bK);                                     \
    CVT_V(vv0, 0, bV); CVT_V(vv1, 1, bV); } while (0)

__global__ __launch_bounds__(512, 4)
void swattn_kernel(const float* __restrict__ Qg, const float* __restrict__ Kg,
                   const float* __restrict__ Vg, float* __restrict__ Og) {
    __shared__ __align__(16) __bf16 smem[SMEM_ELEMS];

    const int t   = threadIdx.x;
    const int w   = t >> 6;        // wave 0..7
    const int l   = t & 63;        // lane
    const int r16 = l & 15;
    const int g4  = l >> 4;        // quarter-wave 0..3
    const int Qlo = blockIdx.x * BQ;
    const int h   = blockIdx.y;
    const int b   = blockIdx.z;

    const size_t bh = ((size_t)b * S_LEN) * SROW + (size_t)h * DD;
    const float C1 = 0.08838834764831845f * 1.44269504088896340f;  // scale * log2(e)

    // ---------- stage Q tile -> LDS bf16, C1 pre-folded ----------
    for (int it = 0; it < 8; ++it) {
        int f   = it * 512 + t;
        int q_l = f >> 5;          // 0..127
        int dq  = (f & 31) * 4;
        const float4 v = *(const float4*)&Qg[bh + (size_t)(Qlo + q_l) * SROW + dq];
        bf16x4 o4 = { (__bf16)(v.x * C1), (__bf16)(v.y * C1),
                      (__bf16)(v.z * C1), (__bf16)(v.w * C1) };
        *(bf16x4*)&smem[q_l * RSQ + dq] = o4;
    }
    __syncthreads();

    bf16x8 qf[4];   // B-operand frags, n=q=lane&15, k=d (wave owns 16 q)
#pragma unroll
    for (int sl = 0; sl < 4; ++sl)
        qf[sl] = *(const bf16x8*)&smem[(w*16 + r16) * RSQ + sl*32 + g4*8];
    __syncthreads();

    const f32x4 zero4 = {0.f, 0.f, 0.f, 0.f};
    f32x4 oacc[8];   // O^T frags: lane holds d=dg*16+4*g4+reg, q=r16
#pragma unroll
    for (int dg = 0; dg < 8; ++dg) oacc[dg] = zero4;
    float m_run = -1e4f;   // finite init: masked exp2 underflows to exact 0
    float l_run = 0.f;

    const int q_w = Qlo + w * 16;   // wave's first query
    const int gv = l >> 5;          // V-staging: which key of the pair
    const int rv = l & 31;          // V-staging: d-quad index

    // staging geometry
    const int kRow = t >> 5;          // 0..15
    const int kCol = (t & 31) * 4;    // 0..124
    const float* Kp = Kg + bh + kCol;
    const float* Vp = Vg + bh + (size_t)(w*4 + gv) * SROW + 4*rv;

    int cb = Qlo - (WIN2 - 1);
    if (cb < 0) cb = 0;
    cb &= ~(BK - 1);
    const int Qhi = Qlo + BQ - 1;

    // T14 prefetch: 4 named float4 = 16 VGPRs live across compute (fits now:
    // st shrank 16->8 acc regs with BK=32, so unified budget has headroom).
    float4 kv0, kv1, vv0, vv1;

    // ---------- prologue: load + stage chunk 0 into buf0 ----------
    LOAD_CHUNK(cb);
    STAGE_WRITE(0, OFF_V0);
    __syncthreads();

    int ph = 0;
    for (int c0 = cb; c0 <= Qhi; c0 += BK) {
        const bool pfn = (c0 + BK <= Qhi);     // block-uniform
        if (pfn) LOAD_CHUNK(c0 + BK);          // issue-early: latency hides under compute

        const int bK = ph ? OFF_K1 : 0;
        const int bV = ph ? OFF_V1 : OFF_V0;

        const bool act = (q_w + 15 >= c0) && (q_w <= c0 + (BK - 1) + (WIN2 - 1));
        if (act) {
            // ---- S^T = K · Q^T : lane: key=kg*16+4*g4+reg, q=r16 ----
            f32x4 st[2] = { zero4, zero4 };
            __builtin_amdgcn_s_setprio(1);
#pragma unroll
            for (int sl = 0; sl < 4; ++sl)
#pragma unroll
                for (int kg = 0; kg < 2; ++kg) {
                    bf16x8 kf = *(const bf16x8*)&smem[bK + (kg*16 + r16) * RSQ + sl*32 + g4*8];
                    st[kg] = mfma16(kf, qf[sl], st[kg]);
                }
            __builtin_amdgcn_s_setprio(0);

            // ---- mask (C1 already folded into Q) ----
            const bool fv = (q_w >= c0 + (BK - 1)) && (q_w + 15 <= c0 + (WIN2 - 1));
            if (!fv) {
                int iq = q_w + r16;
#pragma unroll
                for (int kg = 0; kg < 2; ++kg) {
                    int relb = iq - (c0 + kg*16 + 4*g4);
#pragma unroll
                    for (int rg = 0; rg < 4; ++rg) {
                        bool ok = ((unsigned)(relb - rg)) < (unsigned)WIN2;
                        st[kg][rg] = ok ? st[kg][rg] : -1e30f;
                    }
                }
            }

            // ---- online softmax with defer-max (T13) ----
            float mc = -1e30f;
#pragma unroll
            for (int kg = 0; kg < 2; ++kg)
#pragma unroll
                for (int rg = 0; rg < 4; ++rg) mc = fmaxf(mc, st[kg][rg]);
            mc = fmaxf(mc, __shfl_xor(mc, 16));
            mc = fmaxf(mc, __shfl_xor(mc, 32));
            // full path only if some q-row grew by >8 (log2 units): P <= 2^8, fp32-safe
            if (__any(mc - m_run > 8.f)) {
                float mn = fmaxf(m_run, mc);
                float alpha = exp2f(m_run - mn);
                m_run = mn;
                l_run *= alpha;
#pragma unroll
                for (int dg = 0; dg < 8; ++dg)
#pragma unroll
                    for (int rg = 0; rg < 4; ++rg) oacc[dg][rg] *= alpha;
            }
            float sum = 0.f;
#pragma unroll
            for (int kg = 0; kg < 2; ++kg)
#pragma unroll
                for (int rg = 0; rg < 4; ++rg) {
                    float p = exp2f(st[kg][rg] - m_run);   // masked -> exact 0
                    st[kg][rg] = p;
                    sum += p;
                }
            sum += __shfl_xor(sum, 16);
            sum += __shfl_xor(sum, 32);
            l_run += sum;

            // ---- P -> sP [q][key] bf16 (wave-private rows, no dbuf needed) ----
#pragma unroll
            for (int kg = 0; kg < 2; ++kg) {
                f32x4 pv = st[kg];
                bf16x4 p4 = { (__bf16)pv[0], (__bf16)pv[1], (__bf16)pv[2], (__bf16)pv[3] };
                *(bf16x4*)&smem[OFF_P + (w*16 + r16) * RSP + kg*16 + 4*g4] = p4;
            }

            // ---- O^T += V^T · P^T : A=V^T frag (m=d), B=P frag (n=q), k=32 ----
            bf16x8 pf = *(const bf16x8*)&smem[OFF_P + (w*16 + r16) * RSP + g4*8];
            __builtin_amdgcn_s_setprio(1);
#pragma unroll
            for (int dg = 0; dg < 8; ++dg) {
                // un-swizzle: granule g4 ^ ((row>>2)&3), row=dg*16+r16 -> g4 ^ (r16>>2)
                int col = ((g4 ^ (r16 >> 2)) & 3) * 8;
                bf16x8 vf = *(const bf16x8*)&smem[bV + (dg*16 + r16) * RSV + col];
                oacc[dg] = mfma16(vf, pf, oacc[dg]);
            }
            __builtin_amdgcn_s_setprio(0);
        }

        if (pfn) STAGE_WRITE(ph ? 0 : OFF_K1, ph ? OFF_V0 : OFF_V1);  // write-late, other buffer
        __syncthreads();           // single barrier per chunk (dbuf)
        ph ^= 1;
    }

    // ---------- epilogue: normalize and store (float4 along d) ----------
    float inv = 1.f / l_run;
    int q = q_w + r16;
    size_t base = bh + (size_t)q * SROW;
#pragma unroll
    for (int dg = 0; dg < 8; ++dg) {
        f32x4 o = oacc[dg];
        float4 res = { o[0]*inv, o[1]*inv, o[2]*inv, o[3]*inv };
        *(float4*)&Og[base + dg*16 + 4*g4] = res;
    }
}

extern "C" void kernel_launch(void* const* d_in, const int* in_sizes, int n_in,
                              void* d_out, int out_size, void* d_ws, size_t ws_size,
                              hipStream_t stream) {
    const float* q = (const float*)d_in[0];
    const float* k = (const float*)d_in[1];
    const float* v = (const float*)d_in[2];
    float* o = (float*)d_out;
    int B = in_sizes[0] / (S_LEN * NH * DD);
    dim3 grid(S_LEN / BQ, NH, B);
    swattn_kernel<<<grid, 512, 0, stream>>>(q, k, v, o);
}

// Round 4
// 167.178 us; speedup vs baseline: 1.2166x; 1.0077x over previous
//
#include <hip/hip_runtime.h>
#include <math.h>

#define S_LEN 2048
#define NH    16
#define DD    128
#define SROW  (NH*DD)      // 2048 elems between consecutive s
#define WIN2  512          // merged window (two streams union)
#define BQ    128          // queries per workgroup (4 waves x 32 q)
#define BK    32           // keys per chunk
#define RSQ   136          // LDS stride for K/Q rows (128 d + 8 pad)
#define RSV   72           // LDS stride for V^T rows (32 keys + 40 pad, 36 words)
#define RSP   40           // LDS stride for sP rows (32 keys + 8 pad)

typedef __bf16 bf16x8 __attribute__((ext_vector_type(8)));
typedef __bf16 bf16x4 __attribute__((ext_vector_type(4)));
typedef float  f32x4  __attribute__((ext_vector_type(4)));

__device__ __forceinline__ f32x4 mfma16(bf16x8 a, bf16x8 b, f32x4 c) {
    return __builtin_amdgcn_mfma_f32_16x16x32_bf16(a, b, c, 0, 0, 0);
}

__device__ __forceinline__ unsigned int pack_bf16(float lo, float hi) {
    return (unsigned int)__builtin_bit_cast(unsigned short, (__bf16)lo)
         | ((unsigned int)__builtin_bit_cast(unsigned short, (__bf16)hi) << 16);
}

// Shared layout (bf16 elems), double-buffered K/V + wave-private sP:
//   K0 [0, 4352)  V0 [4352, 13568)  K1 [13568, 17920)  V1 [17920, 27136)
//   sP [27136, 32256)  (128 q rows x RSP)
// Q staging transiently overlays [0, 17408) pre-loop.
#define OFF_V0 4352
#define OFF_K1 13568
#define OFF_V1 17920
#define OFF_P  27136
#define SMEM_ELEMS 32256   // 64512 B -> 2 blocks/CU

// ---- staging over NAMED float4 regs (no address taken -> no scratch) ----
#define LOAD_CHUNK(c) do {                                                    \
    kv0 = *(const float4*)(Kp + (size_t)((c) + kRow     ) * SROW);            \
    kv1 = *(const float4*)(Kp + (size_t)((c) + kRow +  8) * SROW);            \
    kv2 = *(const float4*)(Kp + (size_t)((c) + kRow + 16) * SROW);            \
    kv3 = *(const float4*)(Kp + (size_t)((c) + kRow + 24) * SROW);            \
    vv0 = *(const float4*)(Vp + (size_t)((c) + 0) * SROW);                    \
    vv1 = *(const float4*)(Vp + (size_t)((c) + 2) * SROW);                    \
    vv2 = *(const float4*)(Vp + (size_t)((c) + 4) * SROW);                    \
    vv3 = *(const float4*)(Vp + (size_t)((c) + 6) * SROW); } while (0)

#define CVT_K(v, it, bK) do {                                                 \
    bf16x4 o4_ = { (__bf16)(v).x, (__bf16)(v).y, (__bf16)(v).z, (__bf16)(v).w }; \
    *(bf16x4*)&smem[(bK) + (kRow + (it)*8) * RSQ + kCol] = o4_; } while (0)

// V^T[d][k] with granule swizzle: col = ((k>>3) ^ psi(d))*8 + (k&7),
// psi(d) = ((d>>2) ^ (d>>4)) & 3 = (rv ^ (rv>>2)) & 3 for d = 4rv+2gv+j.
// psi injects rv's high bits into the bank index: writes ~4-way (was 8-16),
// reads uniform (conflict-free residues).  Pair-exchange via shfl_xor(32).
#define CVT_V(v4, it, bV) do {                                                \
    const int k0l_ = w*8 + (it)*2;                                            \
    float ox_ = __shfl_xor((v4).x, 32);                                       \
    float oy_ = __shfl_xor((v4).y, 32);                                       \
    float oz_ = __shfl_xor((v4).z, 32);                                       \
    float ow_ = __shfl_xor((v4).w, 32);                                       \
    float lo0_, hi0_, lo1_, hi1_; int d0_;                                    \
    if (gv == 0) { lo0_ = (v4).x; hi0_ = ox_;    lo1_ = (v4).y; hi1_ = oy_;    d0_ = 4*rv; } \
    else         { lo0_ = oz_;    hi0_ = (v4).z; lo1_ = ow_;    hi1_ = (v4).w; d0_ = 4*rv + 2; } \
    int col_ = ((((k0l_) >> 3) ^ rv ^ (rv >> 2)) & 3) * 8 + ((k0l_) & 7);     \
    *(unsigned int*)&smem[(bV) + (d0_    ) * RSV + col_] = pack_bf16(lo0_, hi0_); \
    *(unsigned int*)&smem[(bV) + (d0_ + 1) * RSV + col_] = pack_bf16(lo1_, hi1_); } while (0)

#define STAGE_WRITE(bK, bV) do {                                              \
    CVT_K(kv0, 0, bK); CVT_K(kv1, 1, bK); CVT_K(kv2, 2, bK); CVT_K(kv3, 3, bK); \
    CVT_V(vv0, 0, bV); CVT_V(vv1, 1, bV); CVT_V(vv2, 2, bV); CVT_V(vv3, 3, bV); } while (0)

__global__ __launch_bounds__(256, 2)
void swattn_kernel(const float* __restrict__ Qg, const float* __restrict__ Kg,
                   const float* __restrict__ Vg, float* __restrict__ Og) {
    __shared__ __align__(16) __bf16 smem[SMEM_ELEMS];

    const int t   = threadIdx.x;
    const int w   = t >> 6;        // wave 0..3
    const int l   = t & 63;        // lane
    const int r16 = l & 15;
    const int g4  = l >> 4;        // quarter-wave 0..3
    const int Qlo = blockIdx.x * BQ;
    const int h   = blockIdx.y;
    const int b   = blockIdx.z;

    const size_t bh = ((size_t)b * S_LEN) * SROW + (size_t)h * DD;
    const float C1 = 0.08838834764831845f * 1.44269504088896340f;  // scale * log2(e)

    // ---------- stage Q tile -> LDS bf16, C1 pre-folded ----------
    for (int it = 0; it < 16; ++it) {
        int f   = it * 256 + t;
        int q_l = f >> 5;          // 0..127
        int dq  = (f & 31) * 4;
        const float4 v = *(const float4*)&Qg[bh + (size_t)(Qlo + q_l) * SROW + dq];
        bf16x4 o4 = { (__bf16)(v.x * C1), (__bf16)(v.y * C1),
                      (__bf16)(v.z * C1), (__bf16)(v.w * C1) };
        *(bf16x4*)&smem[q_l * RSQ + dq] = o4;
    }
    __syncthreads();

    // fat wave: 32 q per wave, 2 q-subtiles (qs).  All indices compile-time.
    bf16x8 qf[2][4];
#pragma unroll
    for (int qs = 0; qs < 2; ++qs)
#pragma unroll
        for (int sl = 0; sl < 4; ++sl)
            qf[qs][sl] = *(const bf16x8*)&smem[(w*32 + qs*16 + r16) * RSQ + sl*32 + g4*8];
    __syncthreads();

    const f32x4 zero4 = {0.f, 0.f, 0.f, 0.f};
    f32x4 oacc[2][8];  // O^T frags per qs: lane holds d=dg*16+4*g4+reg, q=r16
#pragma unroll
    for (int qs = 0; qs < 2; ++qs)
#pragma unroll
        for (int dg = 0; dg < 8; ++dg) oacc[qs][dg] = zero4;
    float m_run[2] = { -1e4f, -1e4f };  // finite init: masked exp2 -> exact 0
    float l_part[2] = { 0.f, 0.f };     // per-lane partials; reduced in epilogue

    const int q_w = Qlo + w * 32;   // wave's first query
    const int gv = l >> 5;          // V-staging: which key of the pair
    const int rv = l & 31;          // V-staging: d-quad index

    // staging geometry (256 threads)
    const int kRow = t >> 5;          // 0..7
    const int kCol = (t & 31) * 4;    // 0..124
    const float* Kp = Kg + bh + kCol;
    const float* Vp = Vg + bh + (size_t)(w*8 + gv) * SROW + 4*rv;

    int cb = Qlo - (WIN2 - 1);
    if (cb < 0) cb = 0;
    cb &= ~(BK - 1);
    const int Qhi = Qlo + BQ - 1;

    // T14 prefetch: 8 named float4 = 32 VGPRs live across compute.
    float4 kv0, kv1, kv2, kv3, vv0, vv1, vv2, vv3;

    // ---------- prologue: load + stage chunk 0 into buf0 ----------
    LOAD_CHUNK(cb);
    STAGE_WRITE(0, OFF_V0);
    __syncthreads();

    int ph = 0;
    for (int c0 = cb; c0 <= Qhi; c0 += BK) {
        const bool pfn = (c0 + BK <= Qhi);     // block-uniform
        if (pfn) LOAD_CHUNK(c0 + BK);          // issue-early

        const int bK = ph ? OFF_K1 : 0;
        const int bV = ph ? OFF_V1 : OFF_V0;

        const bool act = (q_w + 31 >= c0) && (q_w <= c0 + (BK - 1) + (WIN2 - 1));
        if (act) {
            // ---- S^T = K · Q^T : kf shared across both q-subtiles ----
            f32x4 st[2][2];
#pragma unroll
            for (int qs = 0; qs < 2; ++qs) { st[qs][0] = zero4; st[qs][1] = zero4; }
            __builtin_amdgcn_s_setprio(1);
#pragma unroll
            for (int sl = 0; sl < 4; ++sl) {
                bf16x8 kf0 = *(const bf16x8*)&smem[bK + (r16     ) * RSQ + sl*32 + g4*8];
                bf16x8 kf1 = *(const bf16x8*)&smem[bK + (16 + r16) * RSQ + sl*32 + g4*8];
#pragma unroll
                for (int qs = 0; qs < 2; ++qs) {
                    st[qs][0] = mfma16(kf0, qf[qs][sl], st[qs][0]);
                    st[qs][1] = mfma16(kf1, qf[qs][sl], st[qs][1]);
                }
            }
            __builtin_amdgcn_s_setprio(0);

#pragma unroll
            for (int qs = 0; qs < 2; ++qs) {
                const int qb = q_w + qs * 16;
                // ---- mask (C1 already folded into Q) ----
                const bool fv = (qb >= c0 + (BK - 1)) && (qb + 15 <= c0 + (WIN2 - 1));
                if (!fv) {
                    int iq = qb + r16;
#pragma unroll
                    for (int kg = 0; kg < 2; ++kg) {
                        int relb = iq - (c0 + kg*16 + 4*g4);
#pragma unroll
                        for (int rg = 0; rg < 4; ++rg) {
                            bool ok = ((unsigned)(relb - rg)) < (unsigned)WIN2;
                            st[qs][kg][rg] = ok ? st[qs][kg][rg] : -1e30f;
                        }
                    }
                }

                // ---- online softmax, defer-max (T13), deferred l-reduce ----
                float mc = -1e30f;
#pragma unroll
                for (int kg = 0; kg < 2; ++kg)
#pragma unroll
                    for (int rg = 0; rg < 4; ++rg) mc = fmaxf(mc, st[qs][kg][rg]);
                mc = fmaxf(mc, __shfl_xor(mc, 16));
                mc = fmaxf(mc, __shfl_xor(mc, 32));
                if (__any(mc - m_run[qs] > 8.f)) {
                    float mn = fmaxf(m_run[qs], mc);
                    float alpha = exp2f(m_run[qs] - mn);
                    m_run[qs] = mn;
                    l_part[qs] *= alpha;
#pragma unroll
                    for (int dg = 0; dg < 8; ++dg)
#pragma unroll
                        for (int rg = 0; rg < 4; ++rg) oacc[qs][dg][rg] *= alpha;
                }
                float sum = 0.f;
#pragma unroll
                for (int kg = 0; kg < 2; ++kg)
#pragma unroll
                    for (int rg = 0; rg < 4; ++rg) {
                        float p = exp2f(st[qs][kg][rg] - m_run[qs]);  // masked -> 0
                        st[qs][kg][rg] = p;
                        sum += p;
                    }
                l_part[qs] += sum;   // cross-lane reduce deferred to epilogue

                // ---- P -> sP [q][key] bf16 (wave-private rows) ----
#pragma unroll
                for (int kg = 0; kg < 2; ++kg) {
                    f32x4 pv = st[qs][kg];
                    bf16x4 p4 = { (__bf16)pv[0], (__bf16)pv[1], (__bf16)pv[2], (__bf16)pv[3] };
                    *(bf16x4*)&smem[OFF_P + (w*32 + qs*16 + r16) * RSP + kg*16 + 4*g4] = p4;
                }
            }

            // ---- O^T += V^T · P^T : vf shared across both q-subtiles ----
            bf16x8 pf0 = *(const bf16x8*)&smem[OFF_P + (w*32      + r16) * RSP + g4*8];
            bf16x8 pf1 = *(const bf16x8*)&smem[OFF_P + (w*32 + 16 + r16) * RSP + g4*8];
            __builtin_amdgcn_s_setprio(1);
#pragma unroll
            for (int dg = 0; dg < 8; ++dg) {
                int col = ((g4 ^ (r16 >> 2) ^ dg) & 3) * 8;   // un-swizzle psi
                bf16x8 vf = *(const bf16x8*)&smem[bV + (dg*16 + r16) * RSV + col];
                oacc[0][dg] = mfma16(vf, pf0, oacc[0][dg]);
                oacc[1][dg] = mfma16(vf, pf1, oacc[1][dg]);
            }
            __builtin_amdgcn_s_setprio(0);
        }

        if (pfn) STAGE_WRITE(ph ? 0 : OFF_K1, ph ? OFF_V0 : OFF_V1);  // write-late
        __syncthreads();           // single barrier per chunk (dbuf)
        ph ^= 1;
    }

    // ---------- epilogue: reduce l, normalize and store ----------
#pragma unroll
    for (int qs = 0; qs < 2; ++qs) {
        float lsum = l_part[qs];
        lsum += __shfl_xor(lsum, 16);
        lsum += __shfl_xor(lsum, 32);
        float inv = 1.f / lsum;
        int q = q_w + qs*16 + r16;
        size_t base = bh + (size_t)q * SROW;
#pragma unroll
        for (int dg = 0; dg < 8; ++dg) {
            f32x4 o = oacc[qs][dg];
            float4 res = { o[0]*inv, o[1]*inv, o[2]*inv, o[3]*inv };
            *(float4*)&Og[base + dg*16 + 4*g4] = res;
        }
    }
}

extern "C" void kernel_launch(void* const* d_in, const int* in_sizes, int n_in,
                              void* d_out, int out_size, void* d_ws, size_t ws_size,
                              hipStream_t stream) {
    const float* q = (const float*)d_in[0];
    const float* k = (const float*)d_in[1];
    const float* v = (const float*)d_in[2];
    float* o = (float*)d_out;
    int B = in_sizes[0] / (S_LEN * NH * DD);
    dim3 grid(S_LEN / BQ, NH, B);
    swattn_kernel<<<grid, 256, 0, stream>>>(q, k, v, o);
}